// Round 2
// baseline (1787.363 us; speedup 1.0000x reference)
//
#include <hip/hip_runtime.h>
#include <hip/hip_bf16.h>

// ---------------------------------------------------------------------------
// MDTA_FOR_VIDEO_Prompted — full-graph HIP implementation, fp32 in/out/compute.
// B=2, C=32, H=W=128. All intermediates fp32 in d_ws.
// ---------------------------------------------------------------------------

constexpr int B = 2, C = 32, H = 128, W = 128, N = H * W;

// ---------------- prep: CAT2=[x;y] NCHW, XT = x NHWC ------------------------
__global__ __launch_bounds__(256) void k_prep(const float* __restrict__ x,
                                              const float* __restrict__ y,
                                              float* __restrict__ cat2,
                                              float* __restrict__ xt) {
  __shared__ float tile[C][257];
  const int b = blockIdx.y, n0 = blockIdx.x * 256, tid = threadIdx.x;
  const int n = n0 + tid;
  for (int c = 0; c < C; c++) {
    float v = x[(size_t)(b * C + c) * N + n];
    tile[c][tid] = v;
    cat2[(size_t)(b * 64 + c) * N + n] = v;
  }
  for (int c = 0; c < C; c++)
    cat2[(size_t)(b * 64 + 32 + c) * N + n] = y[(size_t)(b * C + c) * N + n];
  __syncthreads();
  for (int i = tid; i < C * 256; i += 256) {
    int c = i & 31, nl = i >> 5;
    xt[((size_t)b * N + n0 + nl) * C + c] = tile[c][nl];
  }
}

// ---------------- layernorm over channels ----------------------------------
__global__ __launch_bounds__(256) void k_lnorm(const float* __restrict__ xt,
                                               const float* __restrict__ g,
                                               const float* __restrict__ bta,
                                               float* __restrict__ xn) {
  const int b = blockIdx.y;
  const int n = blockIdx.x * 256 + threadIdx.x;
  const float* p = xt + ((size_t)b * N + n) * C;
  float v[C], s = 0.f, ss = 0.f;
#pragma unroll
  for (int c = 0; c < C; c++) { v[c] = p[c]; s += v[c]; ss += v[c] * v[c]; }
  const float mu = s * (1.f / C);
  const float var = ss * (1.f / C) - mu * mu;
  const float inv = rsqrtf(var + 1e-5f);
#pragma unroll
  for (int c = 0; c < C; c++)
    xn[(size_t)(b * C + c) * N + n] = (v[c] - mu) * inv * g[c] + bta[c];
}

// ---------------- generic 1x1 conv (4 couts/thread) ------------------------
__global__ __launch_bounds__(256)
void k_conv1x1(const float* __restrict__ in, long in_bs, int cin,
               const float* __restrict__ wts, const float* __restrict__ bias,
               const float* __restrict__ resid, long res_bs,
               float* __restrict__ out, long out_bs, int out_coff) {
  const int n = blockIdx.x * 256 + threadIdx.x;
  const int co0 = blockIdx.y * 4, b = blockIdx.z;
  const float* ip = in + (size_t)b * in_bs + n;
  const float* w = wts + (size_t)co0 * cin;
  float a0 = 0, a1 = 0, a2 = 0, a3 = 0;
  for (int ci = 0; ci < cin; ci++) {
    float xv = ip[(size_t)ci * N];
    a0 += xv * w[ci]; a1 += xv * w[cin + ci];
    a2 += xv * w[2 * cin + ci]; a3 += xv * w[3 * cin + ci];
  }
  float acc[4] = {a0, a1, a2, a3};
#pragma unroll
  for (int o = 0; o < 4; o++) {
    const int co = co0 + o;
    float r = acc[o];
    if (bias) r += bias[co];
    if (resid) r += resid[(size_t)b * res_bs + (size_t)co * N + n];
    out[(size_t)b * out_bs + (size_t)(out_coff + co) * N + n] = r;
  }
}

// ---------------- generic 3x3 conv (LDS input tile, scalar weights) --------
template <int TCO>
__global__ __launch_bounds__(256)
void k_conv3(const float* __restrict__ in, long in_bs, int cin, int ih, int iw,
             const float* __restrict__ wts, int cout,
             float* __restrict__ out, long out_bs, int out_coff, int oh, int ow,
             int pad, int tiles_x) {
  constexpr int TW = 32, TH = 8;
  __shared__ float tile[4][TH + 2][TW + 2];
  const int tid = threadIdx.x;
  const int tileid = blockIdx.x, b = blockIdx.z;
  const int tx0 = (tileid % tiles_x) * TW, ty0 = (tileid / tiles_x) * TH;
  const int co0 = blockIdx.y * TCO;
  const int tx = tid & 31, ty = tid >> 5;
  const int ox = tx0 + tx, oy = ty0 + ty;
  float acc[TCO];
#pragma unroll
  for (int o = 0; o < TCO; o++) acc[o] = 0.f;
  const float* inb = in + (size_t)b * in_bs;
  const int isp = ih * iw;
  for (int c0 = 0; c0 < cin; c0 += 4) {
    const int cb = min(4, cin - c0);
    __syncthreads();
    for (int i = tid; i < cb * 340; i += 256) {
      int c = i / 340, rem = i - c * 340;
      int r = rem / 34, col = rem - r * 34;
      int iy = ty0 - pad + r, ix = tx0 - pad + col;
      float v = 0.f;
      if (iy >= 0 && iy < ih && ix >= 0 && ix < iw)
        v = inb[(size_t)(c0 + c) * isp + (size_t)iy * iw + ix];
      tile[c][r][col] = v;
    }
    __syncthreads();
    for (int c = 0; c < cb; c++) {
      const float x0 = tile[c][ty + 0][tx + 0], x1 = tile[c][ty + 0][tx + 1], x2 = tile[c][ty + 0][tx + 2];
      const float x3 = tile[c][ty + 1][tx + 0], x4 = tile[c][ty + 1][tx + 1], x5 = tile[c][ty + 1][tx + 2];
      const float x6 = tile[c][ty + 2][tx + 0], x7 = tile[c][ty + 2][tx + 1], x8 = tile[c][ty + 2][tx + 2];
      const float* wp = wts + ((size_t)co0 * cin + (c0 + c)) * 9;
#pragma unroll
      for (int o = 0; o < TCO; o++) {
        if (co0 + o >= cout) break;
        const float* w = wp + (size_t)o * cin * 9;
        acc[o] += x0 * w[0] + x1 * w[1] + x2 * w[2] + x3 * w[3] + x4 * w[4]
                + x5 * w[5] + x6 * w[6] + x7 * w[7] + x8 * w[8];
      }
    }
  }
  if (ox < ow && oy < oh) {
    const size_t ob = (size_t)b * out_bs + (size_t)oy * ow + ox;
#pragma unroll
    for (int o = 0; o < TCO; o++) {
      const int co = co0 + o;
      if (co < cout) out[ob + (size_t)(out_coff + co) * (size_t)(oh * ow)] = acc[o];
    }
  }
}

// ---------------- grouped 3x3 conv (groups=32, 3 in / 3 out per group) -----
__global__ __launch_bounds__(256) void k_dwconv(const float* __restrict__ in,
                                                const float* __restrict__ wts,
                                                float* __restrict__ out) {
  const int n = blockIdx.x * 256 + threadIdx.x;
  const int g = blockIdx.y, b = blockIdx.z;
  const int h0 = n >> 7, w0 = n & 127;
  float acc[3] = {0.f, 0.f, 0.f};
  for (int ci = 0; ci < 3; ci++) {
    const float* ip = in + ((size_t)b * 96 + g * 3 + ci) * N;
#pragma unroll
    for (int ky = 0; ky < 3; ky++) {
      const int iy = h0 - 1 + ky;
      if (iy < 0 || iy >= H) continue;
#pragma unroll
      for (int kx = 0; kx < 3; kx++) {
        const int ix = w0 - 1 + kx;
        if (ix < 0 || ix >= W) continue;
        const float v = ip[(size_t)iy * W + ix];
#pragma unroll
        for (int o = 0; o < 3; o++)
          acc[o] += v * wts[((size_t)(g * 3 + o) * 3 + ci) * 9 + ky * 3 + kx];
      }
    }
  }
#pragma unroll
  for (int o = 0; o < 3; o++)
    out[((size_t)b * 96 + g * 3 + o) * N + n] = acc[o];
}

// ---------------- channel-attn: norms + gram + softmax ---------------------
template <int DQ>
__global__ __launch_bounds__(256)
void k_attn_stats(const float* __restrict__ q1, long q1_bs,
                  const float* __restrict__ q2, long q2_bs,
                  const float* __restrict__ k, long k_bs,
                  const float* __restrict__ temp, float* __restrict__ stats) {
  const int h = blockIdx.x, b = blockIdx.y, tid = threadIdx.x;
  const float* qp[DQ];
#pragma unroll
  for (int d = 0; d < DQ; d++) {
    const int qc = h * DQ + d;
    qp[d] = (qc < 32) ? (q1 + (size_t)b * q1_bs + (size_t)qc * N)
                      : (q2 + (size_t)b * q2_bs + (size_t)(qc - 32) * N);
  }
  const float* kp[4];
#pragma unroll
  for (int e = 0; e < 4; e++) kp[e] = k + (size_t)b * k_bs + (size_t)(h * 4 + e) * N;

  constexpr int NV = DQ + 4 + DQ * 4;
  float ssq[DQ] = {}, ssk[4] = {}, gr[DQ][4] = {};
  for (int n = tid; n < N; n += 256) {
    float qv[DQ], kv[4];
#pragma unroll
    for (int d = 0; d < DQ; d++) { qv[d] = qp[d][n]; ssq[d] += qv[d] * qv[d]; }
#pragma unroll
    for (int e = 0; e < 4; e++) { kv[e] = kp[e][n]; ssk[e] += kv[e] * kv[e]; }
#pragma unroll
    for (int d = 0; d < DQ; d++)
#pragma unroll
      for (int e = 0; e < 4; e++) gr[d][e] += qv[d] * kv[e];
  }
  float vals[NV];
#pragma unroll
  for (int d = 0; d < DQ; d++) vals[d] = ssq[d];
#pragma unroll
  for (int e = 0; e < 4; e++) vals[DQ + e] = ssk[e];
#pragma unroll
  for (int d = 0; d < DQ; d++)
#pragma unroll
    for (int e = 0; e < 4; e++) vals[DQ + 4 + d * 4 + e] = gr[d][e];
#pragma unroll
  for (int j = 0; j < NV; j++) {
    float v = vals[j];
    for (int m = 32; m > 0; m >>= 1) v += __shfl_xor(v, m, 64);
    vals[j] = v;
  }
  __shared__ float red[4][NV];
  const int wid = tid >> 6, lane = tid & 63;
  if (lane == 0)
#pragma unroll
    for (int j = 0; j < NV; j++) red[wid][j] = vals[j];
  __syncthreads();
  if (tid == 0) {
    float tot[NV];
#pragma unroll
    for (int j = 0; j < NV; j++) tot[j] = red[0][j] + red[1][j] + red[2][j] + red[3][j];
    float invq[DQ], invk[4];
#pragma unroll
    for (int d = 0; d < DQ; d++) invq[d] = 1.f / fmaxf(sqrtf(tot[d]), 1e-12f);
#pragma unroll
    for (int e = 0; e < 4; e++) invk[e] = 1.f / fmaxf(sqrtf(tot[DQ + e]), 1e-12f);
    const float t = temp[h];
    float* sp = stats + (size_t)(b * 8 + h) * DQ * 4;
    for (int d = 0; d < DQ; d++) {
      float s[4], mx = -1e30f;
#pragma unroll
      for (int e = 0; e < 4; e++) {
        s[e] = tot[DQ + 4 + d * 4 + e] * invq[d] * invk[e] * t;
        mx = fmaxf(mx, s[e]);
      }
      float sum = 0.f;
#pragma unroll
      for (int e = 0; e < 4; e++) { s[e] = expf(s[e] - mx); sum += s[e]; }
#pragma unroll
      for (int e = 0; e < 4; e++) sp[d * 4 + e] = s[e] / sum;
    }
  }
}

// ---------------- channel-attn: apply attn to v ----------------------------
template <int DQ>
__global__ __launch_bounds__(256)
void k_attn_apply(const float* __restrict__ v, long v_bs,
                  const float* __restrict__ stats,
                  float* __restrict__ out, long out_bs) {
  const int n = blockIdx.x * 256 + threadIdx.x;
  const int h = blockIdx.y, b = blockIdx.z;
  float vv[4];
#pragma unroll
  for (int e = 0; e < 4; e++) vv[e] = v[(size_t)b * v_bs + (size_t)(h * 4 + e) * N + n];
  const float* A = stats + (size_t)(b * 8 + h) * DQ * 4;
#pragma unroll
  for (int d = 0; d < DQ; d++) {
    const float a = A[d * 4] * vv[0] + A[d * 4 + 1] * vv[1] + A[d * 4 + 2] * vv[2] + A[d * 4 + 3] * vv[3];
    out[(size_t)b * out_bs + (size_t)(h * DQ + d) * N + n] = a;
  }
}

// ---------------- avgpool 2x2 on CAT2 --------------------------------------
__global__ __launch_bounds__(256) void k_avgpool(const float* __restrict__ in,
                                                 float* __restrict__ out) {
  const int id = blockIdx.x * 256 + threadIdx.x;  // B*64*64*64
  const int ox = id & 63, oy = (id >> 6) & 63, c = (id >> 12) & 63, b = id >> 18;
  const float* p = in + ((size_t)b * 64 + c) * N + (size_t)(oy * 2) * W + ox * 2;
  out[id] = 0.25f * (p[0] + p[1] + p[W] + p[W + 1]);
}

// ---------------- t3 *= sigmoid(nearest_resize(asmall)) --------------------
__global__ __launch_bounds__(256) void k_sigmul(float* __restrict__ t3,
                                                const float* __restrict__ asmall) {
  const int id = blockIdx.x * 256 + threadIdx.x;  // B*166*N
  const int x = id & 127, yv = (id >> 7) & 127;
  const int bc = id >> 14;
  const int iy = (yv * 62) >> 7, ix = (x * 62) >> 7;
  const float a = asmall[(size_t)bc * 3844 + iy * 62 + ix];
  t3[id] *= 1.f / (1.f + expf(-a));
}

// ---------------- deformable conv (stride1, groups=8, bilinear) ------------
template <int K>
__global__ __launch_bounds__(256)
void k_deform(const float* __restrict__ xt, const float* __restrict__ offs, int off_c0,
              const float* __restrict__ wd, const float* __restrict__ bd,
              float* __restrict__ out, int out_c0) {
  constexpr int K2 = K * K, PAD = K / 2;
  const int n = blockIdx.x * 256 + threadIdx.x;
  const int g = blockIdx.y, b = blockIdx.z;
  const int hy = n >> 7, wx = n & 127;
  float acc[4] = {0.f, 0.f, 0.f, 0.f};
  const float* ob = offs + (size_t)b * (166 * N) + (size_t)off_c0 * N + n;
  const float* xb = xt + ((size_t)b * N) * 32 + g * 4;
  const float* wg = wd + (size_t)(g * 4) * (4 * K2);
  for (int tap = 0; tap < K2; tap++) {
    const int ky = tap / K, kx = tap % K;
    const float dy = ob[(size_t)(2 * tap) * N];
    const float dx = ob[(size_t)(2 * tap + 1) * N];
    const float py = (float)(hy - PAD + ky) + dy;
    const float px = (float)(wx - PAD + kx) + dx;
    const float y0f = floorf(py), x0f = floorf(px);
    const float fy = py - y0f, fx = px - x0f;
    const int y0 = (int)y0f, x0 = (int)x0f;
    const int y1 = y0 + 1, x1 = x0 + 1;
    float w00 = (1.f - fy) * (1.f - fx), w01 = (1.f - fy) * fx;
    float w10 = fy * (1.f - fx), w11 = fy * fx;
    const bool vy0 = (y0 >= 0) & (y0 < H), vy1 = (y1 >= 0) & (y1 < H);
    const bool vx0 = (x0 >= 0) & (x0 < W), vx1 = (x1 >= 0) & (x1 < W);
    w00 = (vy0 & vx0) ? w00 : 0.f;
    w01 = (vy0 & vx1) ? w01 : 0.f;
    w10 = (vy1 & vx0) ? w10 : 0.f;
    w11 = (vy1 & vx1) ? w11 : 0.f;
    const int cy0 = min(max(y0, 0), H - 1), cy1 = min(max(y1, 0), H - 1);
    const int cx0 = min(max(x0, 0), W - 1), cx1 = min(max(x1, 0), W - 1);
    const float4 g00 = *(const float4*)(xb + (size_t)(cy0 * W + cx0) * 32);
    const float4 g01 = *(const float4*)(xb + (size_t)(cy0 * W + cx1) * 32);
    const float4 g10 = *(const float4*)(xb + (size_t)(cy1 * W + cx0) * 32);
    const float4 g11 = *(const float4*)(xb + (size_t)(cy1 * W + cx1) * 32);
    const float s0 = w00 * g00.x + w01 * g01.x + w10 * g10.x + w11 * g11.x;
    const float s1 = w00 * g00.y + w01 * g01.y + w10 * g10.y + w11 * g11.y;
    const float s2 = w00 * g00.z + w01 * g01.z + w10 * g10.z + w11 * g11.z;
    const float s3 = w00 * g00.w + w01 * g01.w + w10 * g10.w + w11 * g11.w;
    const float* wt = wg + tap;
#pragma unroll
    for (int o = 0; o < 4; o++) {
      const float* wr = wt + (size_t)(o * 4) * K2;
      acc[o] += s0 * wr[0] + s1 * wr[K2] + s2 * wr[2 * K2] + s3 * wr[3 * K2];
    }
  }
#pragma unroll
  for (int o = 0; o < 4; o++) {
    const float r = fmaxf(acc[o] + bd[g * 4 + o], 0.f);
    out[((size_t)b * 96 + (out_c0 + g * 4 + o)) * N + n] = r;
  }
}

// ---------------------------------------------------------------------------
extern "C" void kernel_launch(void* const* d_in, const int* in_sizes, int n_in,
                              void* d_out, int out_size, void* d_ws, size_t ws_size,
                              hipStream_t stream) {
  // All reference dtypes are float32 — use inputs in place.
  const float* fx       = (const float*)d_in[0];
  const float* fy       = (const float*)d_in[1];
  const float* w_temp   = (const float*)d_in[2];
  const float* w_po     = (const float*)d_in[3];
  const float* w_lp1    = (const float*)d_in[4];
  const float* w_lp2    = (const float*)d_in[5];
  const float* ln_g     = (const float*)d_in[6];
  const float* ln_b     = (const float*)d_in[7];
  const float* w_tempin = (const float*)d_in[8];
  const float* w_qkv    = (const float*)d_in[9];
  const float* w_qkvd   = (const float*)d_in[10];
  const float* w_mproj  = (const float*)d_in[11];
  const float* w_c3     = (const float*)d_in[12];
  const float* w_k2     = (const float*)d_in[13];
  const float* w_k3     = (const float*)d_in[14];
  const float* w_k4     = (const float*)d_in[15];
  const float* w_d3     = (const float*)d_in[16];
  const float* b_d3     = (const float*)d_in[17];
  const float* w_d5     = (const float*)d_in[18];
  const float* b_d5     = (const float*)d_in[19];
  const float* w_d7     = (const float*)d_in[20];
  const float* b_d7     = (const float*)d_in[21];
  const float* w_pw     = (const float*)d_in[22];
  const float* b_pw     = (const float*)d_in[23];
  float* ws = (float*)d_ws;

  // ---- workspace layout (fp32 elements), time-multiplexed regions ----
  size_t off = 0;
  auto buf = [&](size_t nelem) { float* p = ws + off; off += nelem; return p; };
  float* CAT2   = buf(2097152);   // [B,64,N] [x;y], lives whole pass
  float* XT     = buf(1048576);   // [B,N,32] x NHWC (lnorm + deform gathers)
  float* R1     = buf(1048576);   // XN, then ATTN
  float* R2     = buf(3145728);   // QKV1, then CAT1, then ATTN2
  float* R3     = buf(3145728);   // QKV2, then POOL+ASMALL
  float* PROMPT = buf(1048576);
  float* R4     = buf(5439488);   // T3, then CAT3+KFEAT
  float* OFFS   = buf(5439488);
  float* STATS  = buf(1024);
  (void)ws_size; (void)out_size; (void)n_in; (void)in_sizes;

  float* XN = R1;     float* ATTN = R1;
  float* QKV1 = R2;   float* CAT1 = R2;   float* ATTN2 = R2;
  float* QKV2 = R3;   float* POOL = R3;   float* ASMALL = R3 + 524288;
  float* T3 = R4;     float* CAT3 = R4;   float* KFEAT = R4 + 3145728;
  float* ST_IN = STATS;        // inner attn: B*8*4*4 = 256
  float* ST_FI = STATS + 256;  // final attn: B*8*8*4 = 512

  const long bs64 = 64L * N, bs32 = 32L * N, bs96 = 96L * N, bs166 = 166L * N;

  // 1. prep CAT2 + XT
  k_prep<<<dim3(N / 256, B), 256, 0, stream>>>(fx, fy, CAT2, XT);
  // 2. layernorm
  k_lnorm<<<dim3(N / 256, B), 256, 0, stream>>>(XT, ln_g, ln_b, XN);
  // 3. qkv 1x1: XN(32) -> QKV1(96)
  k_conv1x1<<<dim3(N / 256, 24, B), 256, 0, stream>>>(
      XN, bs32, 32, w_qkv, nullptr, nullptr, 0, QKV1, bs96, 0);
  // 4. grouped 3x3: QKV1 -> QKV2
  k_dwconv<<<dim3(N / 256, 32, B), 256, 0, stream>>>(QKV1, w_qkvd, QKV2);
  // 5/6. inner channel attention (dq=4): qi,ki,vi slices of QKV2
  k_attn_stats<4><<<dim3(8, B), 256, 0, stream>>>(
      QKV2, bs96, nullptr, 0, QKV2 + bs32, bs96, w_tempin, ST_IN);
  k_attn_apply<4><<<dim3(N / 256, 8, B), 256, 0, stream>>>(
      QKV2 + 2 * bs32, bs96, ST_IN, ATTN, bs32);
  // 7. xg = x + mproj(ATTN) -> CAT1 ch 64..95
  k_conv1x1<<<dim3(N / 256, 8, B), 256, 0, stream>>>(
      ATTN, bs32, 32, w_mproj, nullptr, CAT2, bs64, CAT1, bs96, 64);
  // 8. l1 = lp1(x) -> CAT1 ch 0..31
  k_conv1x1<<<dim3(N / 256, 8, B), 256, 0, stream>>>(
      CAT2, bs64, 32, w_lp1, nullptr, nullptr, 0, CAT1, bs96, 0);
  // 9. l2 = lp2 3x3(x) -> CAT1 ch 32..63
  k_conv3<8><<<dim3(64, 4, B), 256, 0, stream>>>(
      CAT2, bs64, 32, H, W, w_lp2, 32, CAT1, bs96, 32, H, W, 1, 4);
  // 10. prompt = c3 3x3(CAT1)
  k_conv3<8><<<dim3(64, 4, B), 256, 0, stream>>>(
      CAT1, bs96, 96, H, W, w_c3, 32, PROMPT, bs32, 0, H, W, 1, 4);
  // 11. avgpool CAT2 -> POOL
  k_avgpool<<<dim3((B * 64 * 64 * 64) / 256), 256, 0, stream>>>(CAT2, POOL);
  // 12. k2 3x3 valid: POOL(64,64x64) -> ASMALL(166,62x62)
  k_conv3<8><<<dim3(16, 21, B), 256, 0, stream>>>(
      POOL, 64L * 4096, 64, 64, 64, w_k2, 166, ASMALL, 166L * 3844, 0, 62, 62, 0, 2);
  // 13. k3 3x3: CAT2(64) -> T3(166)
  k_conv3<8><<<dim3(64, 21, B), 256, 0, stream>>>(
      CAT2, bs64, 64, H, W, w_k3, 166, T3, bs166, 0, H, W, 1, 4);
  // 14. T3 *= sigmoid(resize(ASMALL))
  k_sigmul<<<dim3((B * 166 * N) / 256), 256, 0, stream>>>(T3, ASMALL);
  // 15. k4 3x3: T3(166) -> OFFS(166)
  k_conv3<8><<<dim3(64, 21, B), 256, 0, stream>>>(
      T3, bs166, 166, H, W, w_k4, 166, OFFS, bs166, 0, H, W, 1, 4);
  // 16-18. deformable convs -> CAT3
  k_deform<3><<<dim3(N / 256, 8, B), 256, 0, stream>>>(XT, OFFS, 0, w_d3, b_d3, CAT3, 0);
  k_deform<5><<<dim3(N / 256, 8, B), 256, 0, stream>>>(XT, OFFS, 18, w_d5, b_d5, CAT3, 32);
  k_deform<7><<<dim3(N / 256, 8, B), 256, 0, stream>>>(XT, OFFS, 68, w_d7, b_d7, CAT3, 64);
  // 19. k_feat = pw 1x1(CAT3) + bias
  k_conv1x1<<<dim3(N / 256, 8, B), 256, 0, stream>>>(
      CAT3, bs96, 96, w_pw, b_pw, nullptr, 0, KFEAT, bs32, 0);
  // 20/21. final channel attention (dq=8): q=[x;prompt], k=KFEAT, v=x
  k_attn_stats<8><<<dim3(8, B), 256, 0, stream>>>(
      CAT2, bs64, PROMPT, bs32, KFEAT, bs32, w_temp, ST_FI);
  k_attn_apply<8><<<dim3(N / 256, 8, B), 256, 0, stream>>>(
      CAT2, bs64, ST_FI, ATTN2, bs64);
  // 22. out = po 1x1(ATTN2) -> d_out (fp32)
  k_conv1x1<<<dim3(N / 256, 8, B), 256, 0, stream>>>(
      ATTN2, bs64, 64, w_po, nullptr, nullptr, 0, (float*)d_out, bs32, 0);
}